// Round 3
// baseline (282.529 us; speedup 1.0000x reference)
//
#include <hip/hip_runtime.h>
#include <math.h>

#define B 4
#define SEQ 8192
#define DIM 1024
#define HEADS 8
#define NCHUNK 512
#define LOG_NCHUNK 9
#define CLEN (SEQ / NCHUNK)      // 16 rows per chunk
#define LOG_CLEN 4
#define LN_EPS 1e-5f

typedef float vf4 __attribute__((ext_vector_type(4)));

// ---------------------------------------------------------------------------
// Pass 1: fused LayerNorm-stats + local EMA carry, WAVE-PER-CHUNK.
// Each wave (64 lanes) owns one chunk; lane holds 16 channels as 4x float4
// at stride 256 floats (coalesced across lanes). LN reduction is a pure
// 6-level __shfl_xor inside the wave: NO LDS, NO barriers -> hipcc never
// force-drains vmcnt, so next-row loads pipeline under the reduce chain.
// NCHUNK=512 -> 512 blocks -> 2 blocks/CU (2 waves/SIMD) for TLP.
// ---------------------------------------------------------------------------
__global__ void __launch_bounds__(256) pass1_kernel(
        const float* __restrict__ x,
        const float* __restrict__ gamma,
        const float* __restrict__ beta,
        const float* __restrict__ alphas,
        float2* __restrict__ stats,
        float4* __restrict__ carry) {
    const int t     = threadIdx.x;
    const int wave  = t >> 6;
    const int lane  = t & 63;
    const int gcid  = blockIdx.x * 4 + wave;       // chunk id in [0, B*NCHUNK)
    const int chunk = gcid & (NCHUNK - 1);
    const int b     = gcid >> LOG_NCHUNK;

    // lane's channels: c_j = lane*4 + j*256  ->  head h_j = (lane>>5) + 2*j
    float a[4], dec[4];
    float4 g[4], be[4];
#pragma unroll
    for (int j = 0; j < 4; ++j) {
        const int h = (lane >> 5) + 2 * j;
        a[j]   = 1.f / (1.f + expf(-alphas[h]));
        dec[j] = 1.f - a[j];
        g[j]   = *(const float4*)(gamma + lane * 4 + j * 256);
        be[j]  = *(const float4*)(beta  + lane * 4 + j * 256);
    }

    const int rowbase = b * SEQ + chunk * CLEN;
    const float4* xp = (const float4*)x + (long)rowbase * (DIM / 4) + lane;

    float4 y[4];
#pragma unroll
    for (int j = 0; j < 4; ++j) y[j] = make_float4(0.f, 0.f, 0.f, 0.f);

    float4 xv[4];
#pragma unroll
    for (int j = 0; j < 4; ++j) xv[j] = xp[j * 64];

    for (int i = 0; i < CLEN; ++i) {
        // prefetch next row; no barrier anywhere, so these stay in flight
        const int ip = (i + 1 < CLEN) ? i + 1 : i;
        float4 xn[4];
#pragma unroll
        for (int j = 0; j < 4; ++j) xn[j] = xp[ip * 256 + j * 64];

        float s = 0.f, ss = 0.f;
#pragma unroll
        for (int j = 0; j < 4; ++j) {
            s  += xv[j].x + xv[j].y + xv[j].z + xv[j].w;
            ss += xv[j].x * xv[j].x + xv[j].y * xv[j].y
                + xv[j].z * xv[j].z + xv[j].w * xv[j].w;
        }
#pragma unroll
        for (int off = 32; off > 0; off >>= 1) {
            s  += __shfl_xor(s, off);
            ss += __shfl_xor(ss, off);
        }
        const float mean = s * (1.f / DIM);
        const float var  = ss * (1.f / DIM) - mean * mean;
        const float rstd = rsqrtf(var + LN_EPS);
        if (lane == 0) stats[rowbase + i] = make_float2(mean, rstd);

#pragma unroll
        for (int j = 0; j < 4; ++j) {
            float4 u;
            u.x = (xv[j].x - mean) * rstd * g[j].x + be[j].x;
            u.y = (xv[j].y - mean) * rstd * g[j].y + be[j].y;
            u.z = (xv[j].z - mean) * rstd * g[j].z + be[j].z;
            u.w = (xv[j].w - mean) * rstd * g[j].w + be[j].w;
            y[j].x = dec[j] * y[j].x + a[j] * u.x;
            y[j].y = dec[j] * y[j].y + a[j] * u.y;
            y[j].z = dec[j] * y[j].z + a[j] * u.z;
            y[j].w = dec[j] * y[j].w + a[j] * u.w;
            xv[j] = xn[j];
        }
    }
#pragma unroll
    for (int j = 0; j < 4; ++j)
        carry[(long)gcid * (DIM / 4) + lane + j * 64] = y[j];
}

// ---------------------------------------------------------------------------
// Pass 2 (tiny): serial scan of chunk carries per channel, IN-PLACE.
// Each thread owns one channel column: read carry[k], overwrite with the
// exclusive prefix, update. unroll 16 batches 16 independent loads ahead
// of the serial FMA chain (L2-resident working set).
// ---------------------------------------------------------------------------
__global__ void __launch_bounds__(64) carry_scan_kernel(
        const float* __restrict__ alphas,
        float* __restrict__ carry) {
    const int tid = blockIdx.x * 64 + threadIdx.x;   // [0, B*DIM)
    const int c   = tid & (DIM - 1);
    const int b   = tid >> 10;
    const int h   = c >> 7;

    const float a = 1.f / (1.f + expf(-alphas[h]));
    const float r = 1.f - a;
    float rn = r;                                    // r^CLEN via squarings
#pragma unroll
    for (int q = 0; q < LOG_CLEN; ++q) rn = rn * rn;

    float* cp = carry + (long)b * NCHUNK * DIM + c;

    float Y = 0.f;
#pragma unroll 16
    for (int k = 0; k < NCHUNK; ++k) {
        const float loc = cp[(long)k * DIM];
        cp[(long)k * DIM] = Y;                       // exclusive prefix
        Y = rn * Y + loc;
    }
}

// ---------------------------------------------------------------------------
// Pass 3: final scan seeded with the true cross-chunk carry; writes out once.
// Wave-per-chunk, no LDS, no barriers. All CLEN row-stats preloaded into
// registers up front (no broadcast load on the serial EMA chain); next row's
// x prefetched across the chain like pass 1. Nontemporal `out` stores keep
// the 134 MB of writes from evicting x out of the 256 MB L3, so this pass's
// x re-read is served by L3 instead of HBM.
// ---------------------------------------------------------------------------
__global__ void __launch_bounds__(256) pass2_kernel(
        const float* __restrict__ x,
        const float2* __restrict__ stats,
        const float* __restrict__ gamma,
        const float* __restrict__ beta,
        const float* __restrict__ alphas,
        const float* __restrict__ paramD,
        const float4* __restrict__ excl,
        float4* __restrict__ out) {
    const int t     = threadIdx.x;
    const int wave  = t >> 6;
    const int lane  = t & 63;
    const int gcid  = blockIdx.x * 4 + wave;
    const int chunk = gcid & (NCHUNK - 1);
    const int b     = gcid >> LOG_NCHUNK;

    float a[4], dec[4];
    float4 g[4], be[4], D[4];
#pragma unroll
    for (int j = 0; j < 4; ++j) {
        const int h = (lane >> 5) + 2 * j;
        a[j]   = 1.f / (1.f + expf(-alphas[h]));
        dec[j] = 1.f - a[j];
        g[j]   = *(const float4*)(gamma  + lane * 4 + j * 256);
        be[j]  = *(const float4*)(beta   + lane * 4 + j * 256);
        D[j]   = *(const float4*)(paramD + lane * 4 + j * 256);
    }

    const int rowbase = b * SEQ + chunk * CLEN;
    const float4* xp = (const float4*)x + (long)rowbase * (DIM / 4) + lane;
    float4*       op = (float4*)out     + (long)rowbase * (DIM / 4) + lane;

    // preload all row stats for this chunk (uniform broadcast loads)
    float2 st[CLEN];
    {
        const float4* sp = (const float4*)(stats + rowbase);
#pragma unroll
        for (int i = 0; i < CLEN; i += 2) {
            const float4 v = sp[i >> 1];
            st[i]     = make_float2(v.x, v.y);
            st[i + 1] = make_float2(v.z, v.w);
        }
    }

    float4 y[4];
#pragma unroll
    for (int j = 0; j < 4; ++j)
        y[j] = excl[(long)gcid * (DIM / 4) + lane + j * 64];

    float4 xv[4];
#pragma unroll
    for (int j = 0; j < 4; ++j) xv[j] = xp[j * 64];

    for (int i = 0; i < CLEN; ++i) {
        const int ip = (i + 1 < CLEN) ? i + 1 : i;
        float4 xn[4];
#pragma unroll
        for (int j = 0; j < 4; ++j) xn[j] = xp[ip * 256 + j * 64];

        const float mean = st[i].x, rstd = st[i].y;
#pragma unroll
        for (int j = 0; j < 4; ++j) {
            float4 u, o;
            u.x = (xv[j].x - mean) * rstd * g[j].x + be[j].x;
            u.y = (xv[j].y - mean) * rstd * g[j].y + be[j].y;
            u.z = (xv[j].z - mean) * rstd * g[j].z + be[j].z;
            u.w = (xv[j].w - mean) * rstd * g[j].w + be[j].w;
            y[j].x = dec[j] * y[j].x + a[j] * u.x;
            y[j].y = dec[j] * y[j].y + a[j] * u.y;
            y[j].z = dec[j] * y[j].z + a[j] * u.z;
            y[j].w = dec[j] * y[j].w + a[j] * u.w;
            o.x = y[j].x + u.x * D[j].x;
            o.y = y[j].y + u.y * D[j].y;
            o.z = y[j].z + u.z * D[j].z;
            o.w = y[j].w + u.w * D[j].w;
            vf4 vo = { o.x, o.y, o.z, o.w };
            __builtin_nontemporal_store(vo, (vf4*)(op + i * 256 + j * 64));
            xv[j] = xn[j];
        }
    }
}

// ---------------------------------------------------------------------------
extern "C" void kernel_launch(void* const* d_in, const int* in_sizes, int n_in,
                              void* d_out, int out_size, void* d_ws, size_t ws_size,
                              hipStream_t stream) {
    const float* x      = (const float*)d_in[0];
    const float* gamma  = (const float*)d_in[1];
    const float* beta   = (const float*)d_in[2];
    const float* alphas = (const float*)d_in[3];
    const float* paramD = (const float*)d_in[4];
    float* out = (float*)d_out;

    char* ws = (char*)d_ws;
    float2* stats = (float2*)ws;                     // 256 KB (1<<18)
    float*  carry = (float*)(ws + (1 << 18));        // 8 MB, scanned in place

    pass1_kernel<<<B * NCHUNK / 4, 256, 0, stream>>>(
        x, gamma, beta, alphas, stats, (float4*)carry);
    carry_scan_kernel<<<B * DIM / 64, 64, 0, stream>>>(alphas, carry);
    pass2_kernel<<<B * NCHUNK / 4, 256, 0, stream>>>(
        x, stats, gamma, beta, alphas, paramD, (const float4*)carry, (float4*)out);
}

// Round 4
// 262.705 us; speedup vs baseline: 1.0755x; 1.0755x over previous
//
#include <hip/hip_runtime.h>
#include <math.h>

#define B 4
#define SEQ 8192
#define DIM 1024
#define HEADS 8
#define NCHUNK 256
#define LOG_NCHUNK 8
#define CLEN (SEQ / NCHUNK)      // 32 rows per chunk
#define LN_EPS 1e-5f

typedef float vf4 __attribute__((ext_vector_type(4)));

// ---------------------------------------------------------------------------
// Pass 1: fused LayerNorm-stats + local EMA carry, WAVE-PER-CHUNK.
// (byte-identical to the 276 µs round-2 version)
// Each wave (64 lanes) owns one chunk; lane holds 16 channels as 4x float4
// at stride 256 floats (coalesced across lanes). LN reduction is a pure
// 6-level __shfl_xor inside the wave: NO LDS, NO barriers -> hipcc never
// force-drains vmcnt, so next-row loads pipeline under the reduce chain.
// ---------------------------------------------------------------------------
__global__ void __launch_bounds__(256) pass1_kernel(
        const float* __restrict__ x,
        const float* __restrict__ gamma,
        const float* __restrict__ beta,
        const float* __restrict__ alphas,
        float2* __restrict__ stats,
        float4* __restrict__ carry) {
    const int t     = threadIdx.x;
    const int wave  = t >> 6;
    const int lane  = t & 63;
    const int gcid  = blockIdx.x * 4 + wave;       // chunk id in [0, B*NCHUNK)
    const int chunk = gcid & (NCHUNK - 1);
    const int b     = gcid >> LOG_NCHUNK;

    // lane's channels: c_j = lane*4 + j*256  ->  head h_j = (lane>>5) + 2*j
    float a[4], dec[4];
    float4 g[4], be[4];
#pragma unroll
    for (int j = 0; j < 4; ++j) {
        const int h = (lane >> 5) + 2 * j;
        a[j]   = 1.f / (1.f + expf(-alphas[h]));
        dec[j] = 1.f - a[j];
        g[j]   = *(const float4*)(gamma + lane * 4 + j * 256);
        be[j]  = *(const float4*)(beta  + lane * 4 + j * 256);
    }

    const int rowbase = b * SEQ + chunk * CLEN;
    const float4* xp = (const float4*)x + (long)rowbase * (DIM / 4) + lane;

    float4 y[4];
#pragma unroll
    for (int j = 0; j < 4; ++j) y[j] = make_float4(0.f, 0.f, 0.f, 0.f);

    float4 xv[4];
#pragma unroll
    for (int j = 0; j < 4; ++j) xv[j] = xp[j * 64];

    for (int i = 0; i < CLEN; ++i) {
        // prefetch next row; no barrier anywhere, so these stay in flight
        const int ip = (i + 1 < CLEN) ? i + 1 : i;
        float4 xn[4];
#pragma unroll
        for (int j = 0; j < 4; ++j) xn[j] = xp[ip * 256 + j * 64];

        float s = 0.f, ss = 0.f;
#pragma unroll
        for (int j = 0; j < 4; ++j) {
            s  += xv[j].x + xv[j].y + xv[j].z + xv[j].w;
            ss += xv[j].x * xv[j].x + xv[j].y * xv[j].y
                + xv[j].z * xv[j].z + xv[j].w * xv[j].w;
        }
#pragma unroll
        for (int off = 32; off > 0; off >>= 1) {
            s  += __shfl_xor(s, off);
            ss += __shfl_xor(ss, off);
        }
        const float mean = s * (1.f / DIM);
        const float var  = ss * (1.f / DIM) - mean * mean;
        const float rstd = rsqrtf(var + LN_EPS);
        if (lane == 0) stats[rowbase + i] = make_float2(mean, rstd);

#pragma unroll
        for (int j = 0; j < 4; ++j) {
            float4 u;
            u.x = (xv[j].x - mean) * rstd * g[j].x + be[j].x;
            u.y = (xv[j].y - mean) * rstd * g[j].y + be[j].y;
            u.z = (xv[j].z - mean) * rstd * g[j].z + be[j].z;
            u.w = (xv[j].w - mean) * rstd * g[j].w + be[j].w;
            y[j].x = dec[j] * y[j].x + a[j] * u.x;
            y[j].y = dec[j] * y[j].y + a[j] * u.y;
            y[j].z = dec[j] * y[j].z + a[j] * u.z;
            y[j].w = dec[j] * y[j].w + a[j] * u.w;
            xv[j] = xn[j];
        }
    }
#pragma unroll
    for (int j = 0; j < 4; ++j)
        carry[(long)gcid * (DIM / 4) + lane + j * 64] = y[j];
}

// ---------------------------------------------------------------------------
// Pass 2 (tiny): serial scan of chunk carries per channel, IN-PLACE.
// (byte-identical to the 276 µs round-2 version)
// ---------------------------------------------------------------------------
__global__ void __launch_bounds__(64) carry_scan_kernel(
        const float* __restrict__ alphas,
        float* __restrict__ carry) {
    const int tid = blockIdx.x * 64 + threadIdx.x;   // [0, B*DIM)
    const int c   = tid & (DIM - 1);
    const int b   = tid >> 10;
    const int h   = c >> 7;

    const float a = 1.f / (1.f + expf(-alphas[h]));
    const float r = 1.f - a;
    float rn = r;                                    // r^32 = r squared 5 times
#pragma unroll
    for (int q = 0; q < 5; ++q) rn = rn * rn;        // CLEN == 32

    float* cp = carry + (long)b * NCHUNK * DIM + c;

    float Y = 0.f;
#pragma unroll 16
    for (int k = 0; k < NCHUNK; ++k) {
        const float loc = cp[(long)k * DIM];
        cp[(long)k * DIM] = Y;                       // exclusive prefix
        Y = rn * Y + loc;
    }
}

// ---------------------------------------------------------------------------
// Pass 3: final scan seeded with the true cross-chunk carry; writes out once.
// Changes vs round 2 (pass3 ONLY is modified this round):
//  - depth-1 x prefetch: next row's 4 loads issue before the serial EMA
//    chain consumes the current row (round-2 pass3 had loads directly on
//    the chain).
//  - stats prefetched one row ahead (uniform 8B load off the chain).
//  - nontemporal out stores: 134 MB of streaming writes stop evicting x
//    from the 256 MB L3, so this pass's x re-read is L3-served.
// ---------------------------------------------------------------------------
__global__ void __launch_bounds__(256) pass2_kernel(
        const float* __restrict__ x,
        const float2* __restrict__ stats,
        const float* __restrict__ gamma,
        const float* __restrict__ beta,
        const float* __restrict__ alphas,
        const float* __restrict__ paramD,
        const float4* __restrict__ excl,
        float4* __restrict__ out) {
    const int t     = threadIdx.x;
    const int wave  = t >> 6;
    const int lane  = t & 63;
    const int gcid  = blockIdx.x * 4 + wave;
    const int chunk = gcid & (NCHUNK - 1);
    const int b     = gcid >> LOG_NCHUNK;

    float a[4], dec[4];
    float4 g[4], be[4], D[4];
#pragma unroll
    for (int j = 0; j < 4; ++j) {
        const int h = (lane >> 5) + 2 * j;
        a[j]   = 1.f / (1.f + expf(-alphas[h]));
        dec[j] = 1.f - a[j];
        g[j]   = *(const float4*)(gamma  + lane * 4 + j * 256);
        be[j]  = *(const float4*)(beta   + lane * 4 + j * 256);
        D[j]   = *(const float4*)(paramD + lane * 4 + j * 256);
    }

    const int rowbase = b * SEQ + chunk * CLEN;
    const float4* xp = (const float4*)x + (long)rowbase * (DIM / 4) + lane;
    float4*       op = (float4*)out     + (long)rowbase * (DIM / 4) + lane;

    float4 y[4];
#pragma unroll
    for (int j = 0; j < 4; ++j)
        y[j] = excl[(long)gcid * (DIM / 4) + lane + j * 64];

    float4 xv[4];
#pragma unroll
    for (int j = 0; j < 4; ++j) xv[j] = xp[j * 64];
    float2 stc = stats[rowbase];

    for (int i = 0; i < CLEN; ++i) {
        const int ip = (i + 1 < CLEN) ? i + 1 : i;
        float4 xn[4];
#pragma unroll
        for (int j = 0; j < 4; ++j) xn[j] = xp[ip * 256 + j * 64];
        const float2 stn = stats[rowbase + ip];      // prefetch next stats

        const float mean = stc.x, rstd = stc.y;
#pragma unroll
        for (int j = 0; j < 4; ++j) {
            float4 u, o;
            u.x = (xv[j].x - mean) * rstd * g[j].x + be[j].x;
            u.y = (xv[j].y - mean) * rstd * g[j].y + be[j].y;
            u.z = (xv[j].z - mean) * rstd * g[j].z + be[j].z;
            u.w = (xv[j].w - mean) * rstd * g[j].w + be[j].w;
            y[j].x = dec[j] * y[j].x + a[j] * u.x;
            y[j].y = dec[j] * y[j].y + a[j] * u.y;
            y[j].z = dec[j] * y[j].z + a[j] * u.z;
            y[j].w = dec[j] * y[j].w + a[j] * u.w;
            o.x = y[j].x + u.x * D[j].x;
            o.y = y[j].y + u.y * D[j].y;
            o.z = y[j].z + u.z * D[j].z;
            o.w = y[j].w + u.w * D[j].w;
            vf4 vo = { o.x, o.y, o.z, o.w };
            __builtin_nontemporal_store(vo, (vf4*)(op + i * 256 + j * 64));
            xv[j] = xn[j];
        }
        stc = stn;
    }
}

// ---------------------------------------------------------------------------
extern "C" void kernel_launch(void* const* d_in, const int* in_sizes, int n_in,
                              void* d_out, int out_size, void* d_ws, size_t ws_size,
                              hipStream_t stream) {
    const float* x      = (const float*)d_in[0];
    const float* gamma  = (const float*)d_in[1];
    const float* beta   = (const float*)d_in[2];
    const float* alphas = (const float*)d_in[3];
    const float* paramD = (const float*)d_in[4];
    float* out = (float*)d_out;

    char* ws = (char*)d_ws;
    float2* stats = (float2*)ws;                     // 256 KB (1<<18)
    float*  carry = (float*)(ws + (1 << 18));        // 4 MB, scanned in place

    pass1_kernel<<<B * NCHUNK / 4, 256, 0, stream>>>(
        x, gamma, beta, alphas, stats, (float4*)carry);
    carry_scan_kernel<<<B * DIM / 64, 64, 0, stream>>>(alphas, carry);
    pass2_kernel<<<B * NCHUNK / 4, 256, 0, stream>>>(
        x, stats, gamma, beta, alphas, paramD, (const float4*)carry, (float4*)out);
}